// Round 4
// baseline (482.852 us; speedup 1.0000x reference)
//
#include <hip/hip_runtime.h>

// AdaCoF sampler: out[b,c,h,w] = sum_k weights[b,k,h,w] * bilinear(image[b,c], y+dy, x+dx)
// B=4, C=3, H=W=256, K2=49.
// R3 post-mortem: still latency-bound (VALU 24%, HBM 16%) - stream->gather
// dependence chain exposed, gathers contend with streams on VMEM pipe.
// R4: single kernel. 16x16 pixel tile/block (512 thr, k split even/odd
// across halves), image halo staged in LDS (gathers -> LDS pipe), streams
// software-pipelined 1 group ahead. Per-tap bounds check + global fallback
// keeps exact correctness for any offset magnitude.

#define BB 4
#define CC 3
#define HH 256
#define WW 256
#define K2 49
#define HWSZ (HH * WW)
#define TS 33                       // padded LDS tile row stride (cells)
#define SCALE (256.0f / 255.0f)

// one bilinear tap: sample at (Ax + dx*SCALE, Ay + dy*SCALE) in tile-relative
// coords, accumulate wgt * bilinear into acc0..2.
#define TAP(DXV, DYV, WGV) do {                                              \
    float pxr = fmaf((DXV), SCALE, Ax);                                      \
    float pyr = fmaf((DYV), SCALE, Ay);                                      \
    pxr = fminf(fmaxf(pxr, cloX), chiX);                                     \
    pyr = fminf(fmaxf(pyr, cloY), chiY);                                     \
    float x0f = floorf(pxr);                                                 \
    float y0f = floorf(pyr);                                                 \
    float wx = pxr - x0f;                                                    \
    float wy = pyr - y0f;                                                    \
    int ix0 = (int)x0f;                                                      \
    int iy0 = (int)y0f;                                                      \
    int ix1 = min(ix0 + 1, iedX);                                            \
    int iy1 = min(iy0 + 1, iedY);                                            \
    bool ok = ((unsigned)ix0 <= 31u) && ((unsigned)ix1 <= 31u) &&            \
              ((unsigned)iy0 <= 31u) && ((unsigned)iy1 <= 31u);              \
    int rA = (iy0 & 31) * TS;                                                \
    int rB = (iy1 & 31) * TS;                                                \
    int cA = ix0 & 31;                                                       \
    int cB = ix1 & 31;                                                       \
    float4 v00 = tile[rA + cA];                                              \
    float4 v01 = tile[rA + cB];                                              \
    float4 v10 = tile[rB + cA];                                              \
    float4 v11 = tile[rB + cB];                                              \
    if (__builtin_expect(!ok, 0)) { /* out of staged halo: exact global path */ \
        int i00 = (iy0 + OY) * WW + (ix0 + OX);                              \
        int i01 = (iy0 + OY) * WW + (ix1 + OX);                              \
        int i10 = (iy1 + OY) * WW + (ix0 + OX);                              \
        int i11 = (iy1 + OY) * WW + (ix1 + OX);                              \
        v00.x = imgB[i00]; v00.y = imgB[HWSZ + i00]; v00.z = imgB[2*HWSZ + i00]; \
        v01.x = imgB[i01]; v01.y = imgB[HWSZ + i01]; v01.z = imgB[2*HWSZ + i01]; \
        v10.x = imgB[i10]; v10.y = imgB[HWSZ + i10]; v10.z = imgB[2*HWSZ + i10]; \
        v11.x = imgB[i11]; v11.y = imgB[HWSZ + i11]; v11.z = imgB[2*HWSZ + i11]; \
    }                                                                        \
    float w11v = wx * wy;                                                    \
    float w10v = wy - w11v;                                                  \
    float w01v = wx - w11v;                                                  \
    float w00v = 1.0f - wx - wy + w11v;                                      \
    w00v *= (WGV); w01v *= (WGV); w10v *= (WGV); w11v *= (WGV);              \
    acc0 = fmaf(v00.x, w00v, fmaf(v01.x, w01v, fmaf(v10.x, w10v, fmaf(v11.x, w11v, acc0)))); \
    acc1 = fmaf(v00.y, w00v, fmaf(v01.y, w01v, fmaf(v10.y, w10v, fmaf(v11.y, w11v, acc1)))); \
    acc2 = fmaf(v00.z, w00v, fmaf(v01.z, w01v, fmaf(v10.z, w10v, fmaf(v11.z, w11v, acc2)))); \
} while (0)

// load stream group G (4 taps) into buffer BUF. half h handles k = 2j+h.
#define LOADG(BUF, G) do {                                                   \
    _Pragma("unroll")                                                        \
    for (int j = 0; j < 4; ++j) {                                            \
        int jj = (G) * 4 + j;                                                \
        dxv[BUF][j] = offB2[(size_t)(4 * jj) * HWSZ];                        \
        dyv[BUF][j] = offB2[(size_t)(4 * jj + 1) * HWSZ];                    \
        wgv[BUF][j] = wgtB2[(size_t)(2 * jj) * HWSZ];                        \
    }                                                                        \
} while (0)

__global__ void __launch_bounds__(512, 6)
adacof_tile(const float* __restrict__ img,
            const float* __restrict__ offsets,
            const float* __restrict__ weights,
            float* __restrict__ out) {
    __shared__ float4 tile[32 * TS];     // 16,896 B (row-padded: +1 cell)
    __shared__ float redbuf[3 * 256];    // 3,072 B

    const int t = threadIdx.x;
    const int h = t >> 8;                // k-half, wave-uniform
    const int pix = t & 255;
    const int tx = pix & 15, ty = pix >> 4;

    const int bidx = blockIdx.x;
    const int b = bidx >> 8;
    const int tIdx = bidx & 255;
    const int X0 = (tIdx & 15) << 4;
    const int Y0 = (tIdx >> 4) << 4;
    const int OX = X0 - 8, OY = Y0 - 8;  // tile origin in image coords

    const float* imgB = img + (size_t)b * (CC * HWSZ);

    // ---- stage 32x32 halo tile, channels packed in float4 ----
    #pragma unroll
    for (int it = 0; it < 2; ++it) {
        int cell = t + it * 512;
        int ry = cell >> 5, rx = cell & 31;
        int gy = min(max(OY + ry, 0), HH - 1);
        int gx = min(max(OX + rx, 0), WW - 1);
        int gi = gy * WW + gx;
        float4 v;
        v.x = imgB[gi];
        v.y = imgB[HWSZ + gi];
        v.z = imgB[2 * HWSZ + gi];
        v.w = 0.0f;
        tile[ry * TS + rx] = v;
    }
    __syncthreads();

    // per-thread constants (tile-relative sampling frame)
    const float Ax = (float)(X0 + tx) * SCALE - 0.5f - (float)OX;
    const float Ay = (float)(Y0 + ty) * SCALE - 0.5f - (float)OY;
    const float cloX = (float)(-OX), chiX = (float)(WW - 1 - OX);
    const float cloY = (float)(-OY), chiY = (float)(HH - 1 - OY);
    const int iedX = WW - 1 - OX, iedY = HH - 1 - OY;

    const int hw = (Y0 + ty) * WW + (X0 + tx);
    const float* offB2 = offsets + (size_t)b * (2 * K2 * HWSZ) + (size_t)(2 * h) * HWSZ + hw;
    const float* wgtB2 = weights + (size_t)b * (K2 * HWSZ) + (size_t)h * HWSZ + hw;

    float acc0 = 0.0f, acc1 = 0.0f, acc2 = 0.0f;
    float dxv[2][4], dyv[2][4], wgv[2][4];

    // prologue: group 0 + (half 0 only) tail tap k=48 in flight
    LOADG(0, 0);
    float dxt = 0.0f, dyt = 0.0f, wgt_t = 0.0f;
    if (h == 0) {
        dxt = offB2[(size_t)96 * HWSZ];
        dyt = offB2[(size_t)97 * HWSZ];
        wgt_t = wgtB2[(size_t)48 * HWSZ];
    }
    __builtin_amdgcn_sched_barrier(0);

    // 6 groups of 4 taps, streams prefetched one group ahead
    #pragma unroll
    for (int g = 0; g < 6; ++g) {
        if (g < 5) LOADG((g + 1) & 1, g + 1);
        __builtin_amdgcn_sched_barrier(0);   // loads issue before this group's compute
        #pragma unroll
        for (int j = 0; j < 4; ++j)
            TAP(dxv[g & 1][j], dyv[g & 1][j], wgv[g & 1][j]);
    }
    if (h == 0) TAP(dxt, dyt, wgt_t);

    // ---- combine halves, write out ----
    if (h == 1) {
        redbuf[pix] = acc0;
        redbuf[256 + pix] = acc1;
        redbuf[512 + pix] = acc2;
    }
    __syncthreads();
    if (h == 0) {
        acc0 += redbuf[pix];
        acc1 += redbuf[256 + pix];
        acc2 += redbuf[512 + pix];
        float* o = out + (size_t)b * (CC * HWSZ) + hw;
        o[0] = acc0;
        o[HWSZ] = acc1;
        o[2 * HWSZ] = acc2;
    }
}

extern "C" void kernel_launch(void* const* d_in, const int* in_sizes, int n_in,
                              void* d_out, int out_size, void* d_ws, size_t ws_size,
                              hipStream_t stream) {
    const float* image = (const float*)d_in[0];
    const float* offsets = (const float*)d_in[1];
    const float* weights = (const float*)d_in[2];
    float* out = (float*)d_out;

    // 4 batches x 256 tiles of 16x16 pixels; 512 threads = 256 pixels x 2 k-halves
    adacof_tile<<<BB * 256, 512, 0, stream>>>(image, offsets, weights, out);
}

// Round 5
// 66.881 us; speedup vs baseline: 7.2196x; 7.2196x over previous
//
#include <hip/hip_runtime.h>

// AdaCoF sampler: out[b,c,h,w] = sum_k weights[b,k,h,w] * bilinear(image[b,c], y+dy, x+dx)
// B=4, C=3, H=W=256, K2=49.
// R4 post-mortem: launch_bounds(512,6) forced VGPR<=85 under a 25x-unrolled
// body -> 749MB scratch spill; float4 LDS gathers -> 2.1e7 bank conflicts.
// R5: back to R3 dataflow, fixed properly:
//  - k split 8 ways ACROSS WAVES of one 512-thr block (wave g: taps g+8j),
//    LDS reduce at end -> no partial pass, no extra 44MB traffic.
//  - full static unroll, phase structure: stream-loads | addr+weights |
//    issue ALL gathers | consume. sched_barrier(0) between phases so the
//    compiler cannot sink loads to uses (R2/R3 failure). ~24 gathers in
//    flight per wave (ILP), TLP reduced (1 block/CU) -- deliberate trade.
//  - no launch_bounds min-occupancy: avoid forced spills.

#define BB 4
#define CC 3
#define HH 256
#define WW 256
#define K2 49
#define HWSZ (HH * WW)
#define SCALE (256.0f / 255.0f)

// ---------- pass 0: interleave image (b,c,h,w) -> (b,h,w,4) float4 ----------
__global__ void __launch_bounds__(256)
adacof_transpose(const float* __restrict__ img, float4* __restrict__ img4) {
    int tid = blockIdx.x * blockDim.x + threadIdx.x;  // b*HW + hw
    int b = tid >> 16;
    int hw = tid & (HWSZ - 1);
    const float* base = img + (size_t)b * (CC * HWSZ) + hw;
    float4 v;
    v.x = base[0];
    v.y = base[HWSZ];
    v.z = base[2 * HWSZ];
    v.w = 0.0f;
    img4[tid] = v;
}

// ---------- main: 512 thr = 64 consecutive pixels x 8 k-groups ----------
__global__ void __launch_bounds__(512)
adacof_fused(const float4* __restrict__ img4,
             const float* __restrict__ offsets,
             const float* __restrict__ weights,
             float* __restrict__ out) {
    __shared__ float redbuf[8][3][64];   // 6 KB

    const int t = threadIdx.x;
    const int g = t >> 6;                // wave index = k-group (wave-uniform)
    const int pix = t & 63;

    const int bid = blockIdx.x;
    const int b = bid >> 10;
    const int hw = ((bid & 1023) << 6) | pix;   // 64-aligned run, same row
    const int x = hw & (WW - 1);
    const int y = hw >> 8;

    const float* offB = offsets + (size_t)b * (2 * K2 * HWSZ) + hw;
    const float* wgtB = weights + (size_t)b * (K2 * HWSZ) + hw;
    const float4* imgB = img4 + (size_t)b * HWSZ;

    const float Ax = (float)x * SCALE - 0.5f;
    const float Ay = (float)y * SCALE - 0.5f;

    // ---- phase A: all stream loads in flight ----
    float dxv[6], dyv[6], wgv[6];
    #pragma unroll
    for (int j = 0; j < 6; ++j) {
        const size_t k = (size_t)(g + 8 * j);
        dxv[j] = offB[(2 * k) * HWSZ];
        dyv[j] = offB[(2 * k + 1) * HWSZ];
        wgv[j] = wgtB[k * HWSZ];
    }
    float dxt = 0.0f, dyt = 0.0f, wgt7 = 0.0f;
    if (g == 0) {                        // wave 0 takes the 49th tap (k=48)
        dxt  = offB[(size_t)96 * HWSZ];
        dyt  = offB[(size_t)97 * HWSZ];
        wgt7 = wgtB[(size_t)48 * HWSZ];
    }
    __builtin_amdgcn_sched_barrier(0);

    // ---- phase B+C: addresses + folded weights, issue ALL gathers ----
    float w00[6], w01[6], w10[6], w11[6];
    float4 v00[6], v01[6], v10[6], v11[6];
    #pragma unroll
    for (int j = 0; j < 6; ++j) {
        float px = fmaf(dxv[j], SCALE, Ax);
        float py = fmaf(dyv[j], SCALE, Ay);
        px = fminf(fmaxf(px, 0.0f), 255.0f);
        py = fminf(fmaxf(py, 0.0f), 255.0f);
        float x0f = floorf(px);
        float y0f = floorf(py);
        float wx = px - x0f;
        float wy = py - y0f;
        int ix0 = (int)x0f;
        int iy0 = (int)y0f;
        int ix1 = min(ix0 + 1, WW - 1);
        int iy1 = min(iy0 + 1, HH - 1);
        float a11 = wx * wy;
        float a10 = wy - a11;
        float a01 = wx - a11;
        float a00 = (1.0f - wx) - a10;
        float wg = wgv[j];
        w00[j] = a00 * wg; w01[j] = a01 * wg;
        w10[j] = a10 * wg; w11[j] = a11 * wg;
        v00[j] = imgB[iy0 * WW + ix0];
        v01[j] = imgB[iy0 * WW + ix1];
        v10[j] = imgB[iy1 * WW + ix0];
        v11[j] = imgB[iy1 * WW + ix1];
    }
    float w00t = 0.0f, w01t = 0.0f, w10t = 0.0f, w11t = 0.0f;
    float4 v00t = {}, v01t = {}, v10t = {}, v11t = {};
    if (g == 0) {
        float px = fmaf(dxt, SCALE, Ax);
        float py = fmaf(dyt, SCALE, Ay);
        px = fminf(fmaxf(px, 0.0f), 255.0f);
        py = fminf(fmaxf(py, 0.0f), 255.0f);
        float x0f = floorf(px);
        float y0f = floorf(py);
        float wx = px - x0f;
        float wy = py - y0f;
        int ix0 = (int)x0f;
        int iy0 = (int)y0f;
        int ix1 = min(ix0 + 1, WW - 1);
        int iy1 = min(iy0 + 1, HH - 1);
        float a11 = wx * wy;
        float a10 = wy - a11;
        float a01 = wx - a11;
        float a00 = (1.0f - wx) - a10;
        w00t = a00 * wgt7; w01t = a01 * wgt7;
        w10t = a10 * wgt7; w11t = a11 * wgt7;
        v00t = imgB[iy0 * WW + ix0];
        v01t = imgB[iy0 * WW + ix1];
        v10t = imgB[iy1 * WW + ix0];
        v11t = imgB[iy1 * WW + ix1];
    }
    __builtin_amdgcn_sched_barrier(0);

    // ---- phase D: consume ----
    float acc0 = 0.0f, acc1 = 0.0f, acc2 = 0.0f;
    #pragma unroll
    for (int j = 0; j < 6; ++j) {
        acc0 = fmaf(v00[j].x, w00[j], fmaf(v01[j].x, w01[j],
               fmaf(v10[j].x, w10[j], fmaf(v11[j].x, w11[j], acc0))));
        acc1 = fmaf(v00[j].y, w00[j], fmaf(v01[j].y, w01[j],
               fmaf(v10[j].y, w10[j], fmaf(v11[j].y, w11[j], acc1))));
        acc2 = fmaf(v00[j].z, w00[j], fmaf(v01[j].z, w01[j],
               fmaf(v10[j].z, w10[j], fmaf(v11[j].z, w11[j], acc2))));
    }
    if (g == 0) {
        acc0 = fmaf(v00t.x, w00t, fmaf(v01t.x, w01t,
               fmaf(v10t.x, w10t, fmaf(v11t.x, w11t, acc0))));
        acc1 = fmaf(v00t.y, w00t, fmaf(v01t.y, w01t,
               fmaf(v10t.y, w10t, fmaf(v11t.y, w11t, acc1))));
        acc2 = fmaf(v00t.z, w00t, fmaf(v01t.z, w01t,
               fmaf(v10t.z, w10t, fmaf(v11t.z, w11t, acc2))));
    }

    // ---- reduce across the 8 waves in LDS ----
    if (g != 0) {
        redbuf[g][0][pix] = acc0;
        redbuf[g][1][pix] = acc1;
        redbuf[g][2][pix] = acc2;
    }
    __syncthreads();
    if (g == 0) {
        #pragma unroll
        for (int gg = 1; gg < 8; ++gg) {
            acc0 += redbuf[gg][0][pix];
            acc1 += redbuf[gg][1][pix];
            acc2 += redbuf[gg][2][pix];
        }
        float* o = out + (size_t)b * (CC * HWSZ) + hw;
        o[0] = acc0;
        o[HWSZ] = acc1;
        o[2 * HWSZ] = acc2;
    }
}

// ---------- fallback: one thread per pixel, all 49 taps (no ws needed) ----------
__global__ void __launch_bounds__(256)
adacof_direct(const float* __restrict__ img,
              const float* __restrict__ offsets,
              const float* __restrict__ weights,
              float* __restrict__ out) {
    int tid = blockIdx.x * blockDim.x + threadIdx.x;
    int b = tid >> 16;
    int hw = tid & (HWSZ - 1);
    int y = hw >> 8;
    int x = hw & (WW - 1);

    const float* offB = offsets + (size_t)b * (2 * K2 * HWSZ) + hw;
    const float* wgtB = weights + (size_t)b * (K2 * HWSZ) + hw;
    const float* imgB = img + (size_t)b * (CC * HWSZ);

    float fx = (float)x;
    float fy = (float)y;
    float acc0 = 0.0f, acc1 = 0.0f, acc2 = 0.0f;

    for (int k = 0; k < K2; ++k) {
        float dx = offB[(size_t)(2 * k) * HWSZ];
        float dy = offB[(size_t)(2 * k + 1) * HWSZ];
        float wgt = wgtB[(size_t)k * HWSZ];

        float px = (fx + dx) * SCALE - 0.5f;
        float py = (fy + dy) * SCALE - 0.5f;
        px = fminf(fmaxf(px, 0.0f), 255.0f);
        py = fminf(fmaxf(py, 0.0f), 255.0f);

        float x0f = floorf(px);
        float y0f = floorf(py);
        float wx = px - x0f;
        float wy = py - y0f;
        int x0 = (int)x0f;
        int y0 = (int)y0f;
        int x1 = min(x0 + 1, WW - 1);
        int y1 = min(y0 + 1, HH - 1);

        int i00 = y0 * WW + x0;
        int i01 = y0 * WW + x1;
        int i10 = y1 * WW + x0;
        int i11 = y1 * WW + x1;

        float w00 = (1.0f - wx) * (1.0f - wy);
        float w01 = wx * (1.0f - wy);
        float w10 = (1.0f - wx) * wy;
        float w11 = wx * wy;

        #pragma unroll
        for (int c = 0; c < CC; ++c) {
            const float* p = imgB + (size_t)c * HWSZ;
            float bil = p[i00] * w00 + p[i01] * w01 + p[i10] * w10 + p[i11] * w11;
            if (c == 0) acc0 = fmaf(wgt, bil, acc0);
            else if (c == 1) acc1 = fmaf(wgt, bil, acc1);
            else acc2 = fmaf(wgt, bil, acc2);
        }
    }

    float* outB = out + (size_t)b * (CC * HWSZ) + hw;
    outB[0] = acc0;
    outB[HWSZ] = acc1;
    outB[2 * HWSZ] = acc2;
}

extern "C" void kernel_launch(void* const* d_in, const int* in_sizes, int n_in,
                              void* d_out, int out_size, void* d_ws, size_t ws_size,
                              hipStream_t stream) {
    const float* image = (const float*)d_in[0];
    const float* offsets = (const float*)d_in[1];
    const float* weights = (const float*)d_in[2];
    float* out = (float*)d_out;

    const size_t img4_bytes = (size_t)BB * HWSZ * 4 * sizeof(float);  // 4 MB

    if (ws_size >= img4_bytes) {
        float4* img4 = (float4*)d_ws;
        adacof_transpose<<<BB * HWSZ / 256, 256, 0, stream>>>(image, img4);
        // 4096 blocks x 512 thr: 64 consecutive pixels x 8 k-groups
        adacof_fused<<<BB * 1024, 512, 0, stream>>>(img4, offsets, weights, out);
    } else {
        adacof_direct<<<BB * HWSZ / 256, 256, 0, stream>>>(image, offsets, weights, out);
    }
}

// Round 6
// 39.465 us; speedup vs baseline: 12.2350x; 1.6947x over previous
//
#include <hip/hip_runtime.h>

// AdaCoF sampler: out[b,c,h,w] = sum_k weights[b,k,h,w] * bilinear(image[b,c], y+dy, x+dx)
// B=4, C=3, H=W=256, K2=49.
// R5 post-mortem: batched VMEM gathers still serialize on distinct cache
// lines in the L1/TA path (~40 lines per divergent gather) -> ~50us floor.
// R6: gathers moved to LDS (64 divergent lanes per ds_read_b32, bank
// conflicts ~2-way = free). Tile 64x4 px (wave = full row -> streams stay
// 256B coalesced), halo 21x81, scalar f32 per channel (no b128 conflicts).
// 2 k-halves across waves + LDS reduce (R5). Stream pipeline: groups of 4,
// prefetch one group ahead, sched_barrier(0) fencing (R5, proven no-spill).
// Correctness backstop: per-tap in-halo flag; cold whole-pixel recompute
// from global after the loop (code exists once -> no R4-style bloat).

#define BB 4
#define CC 3
#define HH 256
#define WW 256
#define K2 49
#define HWSZ (HH * WW)
#define SCALE (256.0f / 255.0f)

#define ROWS 21          // halo rows: [Y0-8, Y0+12]
#define COLS 81          // halo cols: [X0-8, X0+72]
#define NCELL (ROWS * COLS)   // 1701

__global__ void __launch_bounds__(512)
adacof_tile(const float* __restrict__ img,
            const float* __restrict__ offsets,
            const float* __restrict__ weights,
            float* __restrict__ out) {
    __shared__ float tile[CC][NCELL];    // 20,412 B
    __shared__ float redbuf[CC][256];    //  3,072 B

    const int t = threadIdx.x;
    const int h = t >> 8;                // k-half (wave-uniform)
    const int pix = t & 255;
    const int tx = pix & 63;
    const int ty = pix >> 6;             // wave = one 64-px row

    const int bid = blockIdx.x;
    const int b = bid >> 8;
    const int tIdx = bid & 255;
    const int X0 = (tIdx & 3) << 6;      // 4 tile cols of 64
    const int Y0 = (tIdx >> 2) << 2;     // 64 tile rows of 4
    const int OX = X0 - 8, OY = Y0 - 8;

    const float* imgB = img + (size_t)b * (CC * HWSZ);

    // ---- stage halo: 3 channels, clamped-replicated borders ----
    #pragma unroll
    for (int c = 0; c < CC; ++c) {
        const float* p = imgB + (size_t)c * HWSZ;
        for (int i = t; i < NCELL; i += 512) {
            int ry = i / COLS;
            int rx = i - ry * COLS;
            int gy = min(max(OY + ry, 0), HH - 1);
            int gx = min(max(OX + rx, 0), WW - 1);
            tile[c][i] = p[gy * WW + gx];
        }
    }
    __syncthreads();

    const int hw = (Y0 + ty) * WW + X0 + tx;
    const int kbase = h * 24;            // half0: k 0..23 ; half1: k 24..47 + 48
    const float* offH = offsets + (size_t)b * (2 * K2 * HWSZ)
                                + (size_t)(2 * kbase) * HWSZ + hw;
    const float* wgtH = weights + (size_t)b * (K2 * HWSZ)
                                + (size_t)kbase * HWSZ + hw;

    // tile-frame sampling constants (image clamp expressed in tile coords)
    const float Axt = (float)(X0 + tx) * SCALE - 0.5f - (float)OX;
    const float Ayt = (float)(Y0 + ty) * SCALE - 0.5f - (float)OY;
    const float loX = (float)(-OX), hiX = (float)(WW - 1 - OX);
    const float loY = (float)(-OY), hiY = (float)(HH - 1 - OY);

    float acc0 = 0.0f, acc1 = 0.0f, acc2 = 0.0f;
    int badm = 0;

    const float* t0 = &tile[0][0];
    auto TAP = [&](float dx, float dy, float wg) {
        float f1x = fminf(fmaxf(fmaf(dx, SCALE, Axt), loX), hiX);  // image clamp
        float f1y = fminf(fmaxf(fmaf(dy, SCALE, Ayt), loY), hiY);
        float f2x = fminf(fmaxf(f1x, 0.0f), 79.0f);                // halo clamp
        float f2y = fminf(fmaxf(f1y, 0.0f), 19.0f);
        badm |= (f1x != f2x);
        badm |= (f1y != f2y);
        float x0f = floorf(f2x), y0f = floorf(f2y);
        float wx = f2x - x0f, wy = f2y - y0f;
        int i00 = (int)y0f * COLS + (int)x0f;   // border cells replicate -> no x1/y1 clamp
        float a11 = wx * wy;
        float a10 = wy - a11;
        float a01 = wx - a11;
        float a00 = (1.0f - wx) - a10;
        a00 *= wg; a01 *= wg; a10 *= wg; a11 *= wg;
        float v00 = t0[i00], v01 = t0[i00 + 1];
        float v10 = t0[i00 + COLS], v11 = t0[i00 + COLS + 1];
        acc0 = fmaf(v00, a00, fmaf(v01, a01, fmaf(v10, a10, fmaf(v11, a11, acc0))));
        v00 = t0[NCELL + i00]; v01 = t0[NCELL + i00 + 1];
        v10 = t0[NCELL + i00 + COLS]; v11 = t0[NCELL + i00 + COLS + 1];
        acc1 = fmaf(v00, a00, fmaf(v01, a01, fmaf(v10, a10, fmaf(v11, a11, acc1))));
        v00 = t0[2 * NCELL + i00]; v01 = t0[2 * NCELL + i00 + 1];
        v10 = t0[2 * NCELL + i00 + COLS]; v11 = t0[2 * NCELL + i00 + COLS + 1];
        acc2 = fmaf(v00, a00, fmaf(v01, a01, fmaf(v10, a10, fmaf(v11, a11, acc2))));
    };

    // ---- stream pipeline: 6 groups of 4 taps, prefetch one group ahead ----
    float dxv[2][4], dyv[2][4], wgv[2][4];
    #pragma unroll
    for (int j = 0; j < 4; ++j) {
        dxv[0][j] = offH[(size_t)(2 * j) * HWSZ];
        dyv[0][j] = offH[(size_t)(2 * j + 1) * HWSZ];
        wgv[0][j] = wgtH[(size_t)j * HWSZ];
    }
    float dxt = 0.0f, dyt = 0.0f, wgt = 0.0f;
    if (h == 1) {   // tail tap k=48 (plane 96,97 abs = 48,49 rel; wgt 24 rel)
        dxt = offH[(size_t)48 * HWSZ];
        dyt = offH[(size_t)49 * HWSZ];
        wgt = wgtH[(size_t)24 * HWSZ];
    }
    __builtin_amdgcn_sched_barrier(0);

    #pragma unroll
    for (int g = 0; g < 6; ++g) {
        if (g < 5) {
            #pragma unroll
            for (int j = 0; j < 4; ++j) {
                int k = 4 * (g + 1) + j;
                dxv[(g + 1) & 1][j] = offH[(size_t)(2 * k) * HWSZ];
                dyv[(g + 1) & 1][j] = offH[(size_t)(2 * k + 1) * HWSZ];
                wgv[(g + 1) & 1][j] = wgtH[(size_t)k * HWSZ];
            }
        }
        __builtin_amdgcn_sched_barrier(0);   // loads issue before this group's compute
        #pragma unroll
        for (int j = 0; j < 4; ++j)
            TAP(dxv[g & 1][j], dyv[g & 1][j], wgv[g & 1][j]);
    }
    if (h == 1) TAP(dxt, dyt, wgt);

    // ---- cold correctness backstop (offsets ~N(0,1): never taken) ----
    if (__any(badm)) {
        if (badm) {
            const float Axi = (float)(X0 + tx) * SCALE - 0.5f;
            const float Ayi = (float)(Y0 + ty) * SCALE - 0.5f;
            float a0 = 0.0f, a1 = 0.0f, a2 = 0.0f;
            int ntap = (h == 1) ? 25 : 24;
            for (int idx = 0; idx < ntap; ++idx) {
                int k = (idx == 24) ? 48 : (kbase + idx);
                float dx = offsets[(size_t)b * (2 * K2 * HWSZ) + (size_t)(2 * k) * HWSZ + hw];
                float dy = offsets[(size_t)b * (2 * K2 * HWSZ) + (size_t)(2 * k + 1) * HWSZ + hw];
                float wg = weights[(size_t)b * (K2 * HWSZ) + (size_t)k * HWSZ + hw];
                float px = fminf(fmaxf(fmaf(dx, SCALE, Axi), 0.0f), 255.0f);
                float py = fminf(fmaxf(fmaf(dy, SCALE, Ayi), 0.0f), 255.0f);
                float x0f = floorf(px), y0f = floorf(py);
                float wx = px - x0f, wy = py - y0f;
                int ix0 = (int)x0f, iy0 = (int)y0f;
                int ix1 = min(ix0 + 1, WW - 1), iy1 = min(iy0 + 1, HH - 1);
                float w11 = wx * wy, w10 = wy - w11, w01 = wx - w11;
                float w00 = (1.0f - wx) - w10;
                #pragma unroll
                for (int c = 0; c < CC; ++c) {
                    const float* p = imgB + (size_t)c * HWSZ;
                    float bil = p[iy0 * WW + ix0] * w00 + p[iy0 * WW + ix1] * w01
                              + p[iy1 * WW + ix0] * w10 + p[iy1 * WW + ix1] * w11;
                    if (c == 0) a0 = fmaf(wg, bil, a0);
                    else if (c == 1) a1 = fmaf(wg, bil, a1);
                    else a2 = fmaf(wg, bil, a2);
                }
            }
            acc0 = a0; acc1 = a1; acc2 = a2;
        }
    }

    // ---- combine halves, write out ----
    if (h == 1) {
        redbuf[0][pix] = acc0;
        redbuf[1][pix] = acc1;
        redbuf[2][pix] = acc2;
    }
    __syncthreads();
    if (h == 0) {
        acc0 += redbuf[0][pix];
        acc1 += redbuf[1][pix];
        acc2 += redbuf[2][pix];
        float* o = out + (size_t)b * (CC * HWSZ) + hw;
        o[0] = acc0;
        o[HWSZ] = acc1;
        o[2 * HWSZ] = acc2;
    }
}

extern "C" void kernel_launch(void* const* d_in, const int* in_sizes, int n_in,
                              void* d_out, int out_size, void* d_ws, size_t ws_size,
                              hipStream_t stream) {
    const float* image = (const float*)d_in[0];
    const float* offsets = (const float*)d_in[1];
    const float* weights = (const float*)d_in[2];
    float* out = (float*)d_out;

    // 4 batches x 256 tiles (64x4 px); 512 threads = 256 px x 2 k-halves
    adacof_tile<<<BB * 256, 512, 0, stream>>>(image, offsets, weights, out);
}

// Round 7
// 35.771 us; speedup vs baseline: 13.4983x; 1.1033x over previous
//
#include <hip/hip_runtime.h>

// AdaCoF sampler: out[b,c,h,w] = sum_k weights[b,k,h,w] * bilinear(image[b,c], y+dy, x+dx)
// B=4, C=3, H=W=256, K2=49.
// R6 post-mortem: LDS-gather won (39.5us) but now LDS *instruction* bound:
// 12x ds_read_b32 per tap ~= 37us of LDS issue. LDS pipe is issue-limited,
// not data-limited (256B/clock).
// R7: widen LDS reads 3x:
//  - ch0+ch1 packed float2 -> corner = ds_read_b64; x-pairs merge into
//    ds_read2_b64 (offsets {i,i+1},{i+81,i+82} fit 8-bit). ch2 scalar f32
//    -> 2x ds_read2_b32. 12 instrs/tap -> ~4.
//  - halo border replication == reference clamp (verified all borders,
//    incl. px=255.5 edge case) -> no min/max clamp chain in hot path;
//    in-halo test is just |dx|>7 | |dy|>7 (cold global recompute backstop).
// Kept from R6: 64x4 tile (wave = row -> coalesced streams), 2 k-halves
// across block halves + LDS reduce, stream prefetch one group ahead with
// sched_barrier(0) fencing, no forced occupancy.

#define BB 4
#define CC 3
#define HH 256
#define WW 256
#define K2 49
#define HWSZ (HH * WW)
#define SCALE (256.0f / 255.0f)

#define ROWS 21          // halo rows: [Y0-8, Y0+12]
#define COLS 81          // halo cols: [X0-8, X0+72]
#define NCELL (ROWS * COLS)   // 1701

__global__ void __launch_bounds__(512)
adacof_tile(const float* __restrict__ img,
            const float* __restrict__ offsets,
            const float* __restrict__ weights,
            float* __restrict__ out) {
    __shared__ float2 t01[NCELL];        // ch0,ch1 packed: 13,608 B
    __shared__ float  t2[NCELL];         // ch2:             6,804 B
    __shared__ float  redbuf[CC][256];   //                  3,072 B

    const int t = threadIdx.x;
    const int h = t >> 8;                // k-half (wave-uniform)
    const int pix = t & 255;
    const int tx = pix & 63;
    const int ty = pix >> 6;             // wave = one 64-px row

    const int bid = blockIdx.x;
    const int b = bid >> 8;
    const int tIdx = bid & 255;
    const int X0 = (tIdx & 3) << 6;      // 4 tile cols of 64
    const int Y0 = (tIdx >> 2) << 2;     // 64 tile rows of 4
    const int OX = X0 - 8, OY = Y0 - 8;

    const float* imgB = img + (size_t)b * (CC * HWSZ);

    // ---- stage halo: clamped-replicated borders ----
    {
        const float* p0 = imgB;
        const float* p1 = imgB + HWSZ;
        const float* p2 = imgB + 2 * HWSZ;
        for (int i = t; i < NCELL; i += 512) {
            int ry = i / COLS;
            int rx = i - ry * COLS;
            int gy = min(max(OY + ry, 0), HH - 1);
            int gx = min(max(OX + rx, 0), WW - 1);
            int gi = gy * WW + gx;
            t01[i] = make_float2(p0[gi], p1[gi]);
            t2[i] = p2[gi];
        }
    }
    __syncthreads();

    const int hw = (Y0 + ty) * WW + X0 + tx;
    const int kbase = h * 24;            // half0: k 0..23 ; half1: k 24..47 + 48
    const float* offH = offsets + (size_t)b * (2 * K2 * HWSZ)
                                + (size_t)(2 * kbase) * HWSZ + hw;
    const float* wgtH = weights + (size_t)b * (K2 * HWSZ)
                                + (size_t)kbase * HWSZ + hw;

    // tile-frame sampling constants. With border replication, un-clamped
    // halo sampling == reference's image-clamped sampling whenever
    // |dx|,|dy| <= 7 (then px in [0.47,78.6], py in [0.47,19.6]).
    const float Axt = (float)(X0 + tx) * SCALE - 0.5f - (float)OX;
    const float Ayt = (float)(Y0 + ty) * SCALE - 0.5f - (float)OY;

    float acc0 = 0.0f, acc1 = 0.0f, acc2 = 0.0f;
    int badm = 0;

    auto TAP = [&](float dx, float dy, float wg) {
        badm |= (fabsf(dx) > 7.0f) | (fabsf(dy) > 7.0f);
        float px = fmaf(dx, SCALE, Axt);
        float py = fmaf(dy, SCALE, Ayt);
        px = fminf(fmaxf(px, 0.0f), 79.0f);   // defensive only (badm covers correctness)
        py = fminf(fmaxf(py, 0.0f), 19.0f);
        float x0f = floorf(px), y0f = floorf(py);
        float wx = px - x0f, wy = py - y0f;
        int i00 = (int)y0f * COLS + (int)x0f;
        float a11 = wx * wy;
        float a10 = wy - a11;
        float a01 = wx - a11;
        float a00 = (1.0f - wx) - a10;
        a00 *= wg; a01 *= wg; a10 *= wg; a11 *= wg;
        float2 c00 = t01[i00];
        float2 c01 = t01[i00 + 1];
        float2 c10 = t01[i00 + COLS];
        float2 c11 = t01[i00 + COLS + 1];
        float d00 = t2[i00];
        float d01 = t2[i00 + 1];
        float d10 = t2[i00 + COLS];
        float d11 = t2[i00 + COLS + 1];
        acc0 = fmaf(c00.x, a00, fmaf(c01.x, a01, fmaf(c10.x, a10, fmaf(c11.x, a11, acc0))));
        acc1 = fmaf(c00.y, a00, fmaf(c01.y, a01, fmaf(c10.y, a10, fmaf(c11.y, a11, acc1))));
        acc2 = fmaf(d00, a00, fmaf(d01, a01, fmaf(d10, a10, fmaf(d11, a11, acc2))));
    };

    // ---- stream pipeline: 6 groups of 4 taps, prefetch one group ahead ----
    float dxv[2][4], dyv[2][4], wgv[2][4];
    #pragma unroll
    for (int j = 0; j < 4; ++j) {
        dxv[0][j] = offH[(size_t)(2 * j) * HWSZ];
        dyv[0][j] = offH[(size_t)(2 * j + 1) * HWSZ];
        wgv[0][j] = wgtH[(size_t)j * HWSZ];
    }
    float dxt = 0.0f, dyt = 0.0f, wgt = 0.0f;
    if (h == 1) {   // tail tap k=48 (rel planes 48,49; rel weight 24)
        dxt = offH[(size_t)48 * HWSZ];
        dyt = offH[(size_t)49 * HWSZ];
        wgt = wgtH[(size_t)24 * HWSZ];
    }
    __builtin_amdgcn_sched_barrier(0);

    #pragma unroll
    for (int g = 0; g < 6; ++g) {
        if (g < 5) {
            #pragma unroll
            for (int j = 0; j < 4; ++j) {
                int k = 4 * (g + 1) + j;
                dxv[(g + 1) & 1][j] = offH[(size_t)(2 * k) * HWSZ];
                dyv[(g + 1) & 1][j] = offH[(size_t)(2 * k + 1) * HWSZ];
                wgv[(g + 1) & 1][j] = wgtH[(size_t)k * HWSZ];
            }
        }
        __builtin_amdgcn_sched_barrier(0);   // loads issue before this group's compute
        #pragma unroll
        for (int j = 0; j < 4; ++j)
            TAP(dxv[g & 1][j], dyv[g & 1][j], wgv[g & 1][j]);
    }
    if (h == 1) TAP(dxt, dyt, wgt);

    // ---- cold correctness backstop (offsets ~N(0,1): never taken) ----
    if (__any(badm)) {
        if (badm) {
            const float Axi = (float)(X0 + tx) * SCALE - 0.5f;
            const float Ayi = (float)(Y0 + ty) * SCALE - 0.5f;
            float a0 = 0.0f, a1 = 0.0f, a2 = 0.0f;
            int ntap = (h == 1) ? 25 : 24;
            for (int idx = 0; idx < ntap; ++idx) {
                int k = (idx == 24) ? 48 : (kbase + idx);
                float dx = offsets[(size_t)b * (2 * K2 * HWSZ) + (size_t)(2 * k) * HWSZ + hw];
                float dy = offsets[(size_t)b * (2 * K2 * HWSZ) + (size_t)(2 * k + 1) * HWSZ + hw];
                float wg = weights[(size_t)b * (K2 * HWSZ) + (size_t)k * HWSZ + hw];
                float px = fminf(fmaxf(fmaf(dx, SCALE, Axi), 0.0f), 255.0f);
                float py = fminf(fmaxf(fmaf(dy, SCALE, Ayi), 0.0f), 255.0f);
                float x0f = floorf(px), y0f = floorf(py);
                float wx = px - x0f, wy = py - y0f;
                int ix0 = (int)x0f, iy0 = (int)y0f;
                int ix1 = min(ix0 + 1, WW - 1), iy1 = min(iy0 + 1, HH - 1);
                float w11 = wx * wy, w10 = wy - w11, w01 = wx - w11;
                float w00 = (1.0f - wx) - w10;
                #pragma unroll
                for (int c = 0; c < CC; ++c) {
                    const float* p = imgB + (size_t)c * HWSZ;
                    float bil = p[iy0 * WW + ix0] * w00 + p[iy0 * WW + ix1] * w01
                              + p[iy1 * WW + ix0] * w10 + p[iy1 * WW + ix1] * w11;
                    if (c == 0) a0 = fmaf(wg, bil, a0);
                    else if (c == 1) a1 = fmaf(wg, bil, a1);
                    else a2 = fmaf(wg, bil, a2);
                }
            }
            acc0 = a0; acc1 = a1; acc2 = a2;
        }
    }

    // ---- combine halves, write out ----
    if (h == 1) {
        redbuf[0][pix] = acc0;
        redbuf[1][pix] = acc1;
        redbuf[2][pix] = acc2;
    }
    __syncthreads();
    if (h == 0) {
        acc0 += redbuf[0][pix];
        acc1 += redbuf[1][pix];
        acc2 += redbuf[2][pix];
        float* o = out + (size_t)b * (CC * HWSZ) + hw;
        o[0] = acc0;
        o[HWSZ] = acc1;
        o[2 * HWSZ] = acc2;
    }
}

extern "C" void kernel_launch(void* const* d_in, const int* in_sizes, int n_in,
                              void* d_out, int out_size, void* d_ws, size_t ws_size,
                              hipStream_t stream) {
    const float* image = (const float*)d_in[0];
    const float* offsets = (const float*)d_in[1];
    const float* weights = (const float*)d_in[2];
    float* out = (float*)d_out;

    // 4 batches x 256 tiles (64x4 px); 512 threads = 256 px x 2 k-halves
    adacof_tile<<<BB * 256, 512, 0, stream>>>(image, offsets, weights, out);
}